// Round 4
// baseline (360.045 us; speedup 1.0000x reference)
//
#include <hip/hip_runtime.h>
#include <stdint.h>

#define DD 64
#define RR 5
#define NWAVES 4
#define BLOCK 256

typedef float f32x4  __attribute__((ext_vector_type(4)));
typedef float f32x16 __attribute__((ext_vector_type(16)));
typedef short short8 __attribute__((ext_vector_type(8)));
typedef __bf16 bf16x8 __attribute__((ext_vector_type(8)));
union BF8 { bf16x8 h; short8 s; };

__device__ __forceinline__ short8 pack_bf16(f32x4 a, f32x4 b) {
    BF8 u;
#pragma unroll
    for (int j = 0; j < 4; ++j) { u.h[j] = (__bf16)a[j]; u.h[4 + j] = (__bf16)b[j]; }
    return u.s;
}

// 32 edges/group, one wave per group iteration, all 5 ratings.
//   t[k,e] = sum_l Q[r][k][l] * m[e][l]  via mfma_f32_32x32x16_bf16:
//     A = Q k-tile from LDS (row = lane&31 -> k, l = (lane>>5)*8+j), fragment-order layout
//     B = m rows gathered to reg (col = lane&31 -> e, l = (lane>>5)*8+j)
//     C: col e = lane&31, row k_local = (reg&3) + 8*(reg>>2) + 4*(lane>>5)  (m74/m101 layout)
//   logit[e,r] = sum_k u[e,k]*t[k,e]: 32 fp32 FMAs/lane + ONE shfl_xor(32).
__launch_bounds__(BLOCK, 3)
__global__ void bilinear_decoder_kernel(
    const float* __restrict__ z_user,
    const float* __restrict__ z_movie,
    const int*   __restrict__ eidx,   // [2, E]
    const float* __restrict__ Qm,     // [R, D, D]
    float*       __restrict__ out,    // [E, R]
    int E)
{
    __shared__ short8 qfrag[RR * 8][64];   // 40KB: Q bf16, MFMA-A fragment order (conflict-free b128 reads)
    __shared__ float  st[NWAVES][160];     // 2.5KB per-wave store staging (no barriers)

    const int tid  = threadIdx.x;
    const int wid  = tid >> 6;
    const int lane = tid & 63;
    const int e32  = lane & 31;
    const int hi   = lane >> 5;

    // ---- Q -> LDS, fragment order: f = (r*2+kt)*4+ks ; elem = Q[r][kt*32+e32][ks*16+hi*8+j] ----
#pragma unroll
    for (int t = 0; t < 10; ++t) {
        const int f  = wid * 10 + t;
        const int r  = f >> 3;
        const int kt = (f >> 2) & 1;
        const int ks = f & 3;
        const float* src = Qm + (((size_t)r * DD + kt * 32 + e32) * DD + ks * 16 + hi * 8);
        qfrag[f][lane] = pack_bf16(*(const f32x4*)src, *(const f32x4*)(src + 4));
    }
    __syncthreads();

    const int ng = (E + 31) >> 5;
    const int NW = (int)gridDim.x * NWAVES;
    int g = (int)blockIdx.x * NWAVES + wid;
    if (g >= ng) return;

    f32x4 mS[8];   // movie row stage: mS[2*ks+p] = m[e32][ks*16+hi*8+4p ..]
    f32x4 uS[8];   // user  row stage: uS[kt*4+g8] = u[e32][kt*32+g8*8+hi*4 ..]
    int iu_n, im_n;

    auto ldidx = [&](int gg, int& a, int& b) {
        gg = gg < ng ? gg : ng - 1;
        int e = (gg << 5) + e32;
        if (e >= E) e = E - 1;
        a = eidx[e];
        b = eidx[E + e];
    };
    auto issue_m = [&](int im) {
        const float* mr = z_movie + ((size_t)im << 6);
#pragma unroll
        for (int ks = 0; ks < 4; ++ks) {
            mS[2 * ks]     = *(const f32x4*)(mr + ks * 16 + hi * 8);
            mS[2 * ks + 1] = *(const f32x4*)(mr + ks * 16 + hi * 8 + 4);
        }
    };
    auto issue_u = [&](int iu) {
        const float* ur = z_user + ((size_t)iu << 6);
#pragma unroll
        for (int kt = 0; kt < 2; ++kt)
#pragma unroll
            for (int g8 = 0; g8 < 4; ++g8)
                uS[kt * 4 + g8] = *(const f32x4*)(ur + kt * 32 + g8 * 8 + hi * 4);
    };

    // ---- prologue ----
    int iu0, im0;
    ldidx(g, iu0, im0);
    issue_m(im0);
    issue_u(iu0);
    ldidx(g + NW, iu_n, im_n);

    for (; g < ng; g += NW) {
        // convert current m stage to MFMA-B fragments, then refill stage for next group
        const short8 Bm0 = pack_bf16(mS[0], mS[1]);
        const short8 Bm1 = pack_bf16(mS[2], mS[3]);
        const short8 Bm2 = pack_bf16(mS[4], mS[5]);
        const short8 Bm3 = pack_bf16(mS[6], mS[7]);
        const int  iu_c = iu_n;
        const bool more = (g + NW) < ng;
        if (more) issue_m(im_n);

        float lg[RR];
#pragma unroll
        for (int r = 0; r < RR; ++r) {
            float p = 0.f;
#pragma unroll
            for (int kt = 0; kt < 2; ++kt) {
                const int fb = (r * 2 + kt) * 4;
                f32x16 acc = 0.f;
                acc = __builtin_amdgcn_mfma_f32_32x32x16_bf16(qfrag[fb + 0][lane], Bm0, acc, 0, 0, 0);
                acc = __builtin_amdgcn_mfma_f32_32x32x16_bf16(qfrag[fb + 1][lane], Bm1, acc, 0, 0, 0);
                acc = __builtin_amdgcn_mfma_f32_32x32x16_bf16(qfrag[fb + 2][lane], Bm2, acc, 0, 0, 0);
                acc = __builtin_amdgcn_mfma_f32_32x32x16_bf16(qfrag[fb + 3][lane], Bm3, acc, 0, 0, 0);
                // dot with u at the C-layout rows: k = kt*32 + 8*g8 + 4*hi + j
#pragma unroll
                for (int g8 = 0; g8 < 4; ++g8)
#pragma unroll
                    for (int j = 0; j < 4; ++j)
                        p = fmaf(uS[kt * 4 + g8][j], acc[g8 * 4 + j], p);
            }
            p += __shfl_xor(p, 32);   // combine the two k-halves; all 64 lanes get full logit
            lg[r] = p;
        }
        if (more) { issue_u(iu_c); ldidx(g + 2 * NW, iu_n, im_n); }

        // ---- in-register log_softmax ----
        float mx = fmaxf(fmaxf(fmaxf(lg[0], lg[1]), fmaxf(lg[2], lg[3])), lg[4]);
        float s = 0.f;
#pragma unroll
        for (int r = 0; r < RR; ++r) s += __expf(lg[r] - mx);
        const float sub = mx + __logf(s);

        // ---- stage 160 floats (stride-5 writes: conflict-free), then coalesced store ----
        if (hi == 0) {
            st[wid][e32 * 5 + 0] = lg[0] - sub;
            st[wid][e32 * 5 + 1] = lg[1] - sub;
            st[wid][e32 * 5 + 2] = lg[2] - sub;
        } else {
            st[wid][e32 * 5 + 3] = lg[3] - sub;
            st[wid][e32 * 5 + 4] = lg[4] - sub;
        }
        float* og = out + (size_t)g * 160;
        og[lane]      = st[wid][lane];
        og[64 + lane] = st[wid][64 + lane];
        if (lane < 32) og[128 + lane] = st[wid][128 + lane];
    }
}

extern "C" void kernel_launch(void* const* d_in, const int* in_sizes, int n_in,
                              void* d_out, int out_size, void* d_ws, size_t ws_size,
                              hipStream_t stream) {
    const float* z_user  = (const float*)d_in[0];
    const float* z_movie = (const float*)d_in[1];
    const int*   eidx    = (const int*)d_in[2];
    const float* Qm      = (const float*)d_in[3];
    float* out = (float*)d_out;

    const int E = in_sizes[2] / 2;
    const int ng = (E + 31) >> 5;
    // 768 blocks x 4 waves: 3 blocks/CU (LDS 43.5KB, VGPR<=168) = 12 waves/CU,
    // exactly resident; each wave grid-strides ~10 groups.
    int nblocks = (ng + NWAVES - 1) / NWAVES;
    if (nblocks > 768) nblocks = 768;

    bilinear_decoder_kernel<<<nblocks, BLOCK, 0, stream>>>(
        z_user, z_movie, eidx, Qm, out, E);
}

// Round 7
// 246.247 us; speedup vs baseline: 1.4621x; 1.4621x over previous
//
#include <hip/hip_runtime.h>
#include <stdint.h>

#define DD 64
#define RR 5
#define NWAVES 4
#define BLOCK 256

typedef float  f32x4   __attribute__((ext_vector_type(4)));
typedef short  short4b __attribute__((ext_vector_type(4)));
typedef short  short8  __attribute__((ext_vector_type(8)));
typedef __bf16 bf16x8  __attribute__((ext_vector_type(8)));
union BF8 { bf16x8 h; short8 s; };

__device__ __forceinline__ short8 pack_bf16(f32x4 a, f32x4 b) {
    BF8 u;
#pragma unroll
    for (int j = 0; j < 4; ++j) { u.h[j] = (__bf16)a[j]; u.h[4 + j] = (__bf16)b[j]; }
    return u.s;
}
__device__ __forceinline__ float bf2f(short h) {
    union { uint32_t u; float f; } v; v.u = ((uint32_t)(unsigned short)h) << 16;
    return v.f;
}

// ---------------- preamble: fp32 tables -> bf16 in workspace ----------------
__global__ void cvt_bf16_kernel(const float* __restrict__ a, int n8a,
                                const float* __restrict__ b, int n8b,
                                unsigned short* __restrict__ oa,
                                unsigned short* __restrict__ ob) {
    int i = blockIdx.x * blockDim.x + threadIdx.x;
    const int stride = gridDim.x * blockDim.x;
    const int tot = n8a + n8b;
    for (; i < tot; i += stride) {
        const float* src; unsigned short* dst; int j;
        if (i < n8a) { src = a; dst = oa; j = i; }
        else         { src = b; dst = ob; j = i - n8a; }
        const float* p = src + (size_t)j * 8;
        *(short8*)(dst + (size_t)j * 8) = pack_bf16(*(const f32x4*)p, *(const f32x4*)(p + 4));
    }
}

// ---------------- main: bf16 tables, Q in LDS fragment order ----------------
// Per wave-iteration: 32 edges (2 half-groups of 16), all 5 ratings.
//   mfma_f32_16x16x32_bf16, verified mapping (rounds 2-3):
//     A = Q_r k-tile from LDS  (row = lane&15 -> k, l = (lane>>4)*8+j)
//     B = m row, DIRECT short8 load from bf16 table (col = lane&15 -> e)
//     C: col e = lane&15, row k_local = (lane>>4)*4+reg
//   Each Q fragment read feeds BOTH halves -> 40 ds_read_b128 per 80 MFMAs.
__launch_bounds__(BLOCK, 3)
__global__ void bilinear_bf16_kernel(
    const unsigned short* __restrict__ zu,   // bf16 [N_u, 64]
    const unsigned short* __restrict__ zm,   // bf16 [N_m, 64]
    const int*   __restrict__ eidx,          // [2, E]
    const float* __restrict__ Qm,            // [R, D, D] fp32
    float*       __restrict__ out,           // [E, R]
    int E)
{
    __shared__ short8 qf[RR * 8][64];        // 40KB, fragment order f = r*8+kt*2+s
    __shared__ float  st[NWAVES][160];       // per-wave store staging

    const int tid  = threadIdx.x;
    const int wid  = tid >> 6;
    const int lane = tid & 63;
    const int q    = lane >> 4;
    const int lm   = lane & 15;

    // Q -> LDS: qf[f][lane] = Q[r][kt*16+lm][s*32+q*8 .. +8] bf16
#pragma unroll
    for (int t = 0; t < 10; ++t) {
        const int f = wid * 10 + t;
        const int r = f >> 3, kt = (f >> 1) & 3, s = f & 1;
        const float* src = Qm + (((size_t)r * DD + kt * 16 + lm) * DD + s * 32 + q * 8);
        qf[f][lane] = pack_bf16(*(const f32x4*)src, *(const f32x4*)(src + 4));
    }
    __syncthreads();

    const int ng = (E + 31) >> 5;            // 32-edge groups
    const int NW = (int)gridDim.x * NWAVES;
    int g = (int)blockIdx.x * NWAVES + wid;
    if (g >= ng) return;

    struct Half { short8 bm0, bm1; short4b u0, u1, u2, u3; };

    auto ldidx = [&](int gg, int h, int& a, int& b) {
        int e = (((gg < ng) ? gg : ng - 1) << 5) + h * 16 + lm;
        if (e >= E) e = E - 1;
        a = eidx[e];
        b = eidx[E + e];
    };
    auto ldrows = [&](int iu, int im, Half& H) {
        const unsigned short* mr = zm + ((size_t)im << 6);
        const unsigned short* ur = zu + ((size_t)iu << 6);
        H.bm0 = *(const short8*)(mr + q * 8);        // s=0 fragment, direct
        H.bm1 = *(const short8*)(mr + 32 + q * 8);   // s=1 fragment, direct
        H.u0  = *(const short4b*)(ur + q * 4);
        H.u1  = *(const short4b*)(ur + 16 + q * 4);
        H.u2  = *(const short4b*)(ur + 32 + q * 4);
        H.u3  = *(const short4b*)(ur + 48 + q * 4);
    };
    auto finish = [&](const float lg[RR], int h) {
        float mx = fmaxf(fmaxf(fmaxf(lg[0], lg[1]), fmaxf(lg[2], lg[3])), lg[4]);
        float ssum = 0.f;
#pragma unroll
        for (int r = 0; r < RR; ++r) ssum += __expf(lg[r] - mx);
        const float sub = mx + __logf(ssum);
        const int b = h * 80 + lm * 5;
        const float v0 = (q == 0) ? lg[0] : (q == 1) ? lg[1] : (q == 2) ? lg[2] : lg[3];
        st[wid][b + q] = v0 - sub;
        if (q == 0) st[wid][b + 4] = lg[4] - sub;
    };
    auto compute2 = [&](const Half& H0, const Half& H1, int gg) {
        float lg0[RR], lg1[RR];
#pragma unroll
        for (int r = 0; r < RR; ++r) {
            float p0 = 0.f, p1 = 0.f;
#pragma unroll
            for (int kt = 0; kt < 4; ++kt) {
                const short8 a0 = qf[r * 8 + kt * 2 + 0][lane];
                const short8 a1 = qf[r * 8 + kt * 2 + 1][lane];
                f32x4 c0 = {0.f, 0.f, 0.f, 0.f}, c1 = {0.f, 0.f, 0.f, 0.f};
                c0 = __builtin_amdgcn_mfma_f32_16x16x32_bf16(a0, H0.bm0, c0, 0, 0, 0);
                c0 = __builtin_amdgcn_mfma_f32_16x16x32_bf16(a1, H0.bm1, c0, 0, 0, 0);
                c1 = __builtin_amdgcn_mfma_f32_16x16x32_bf16(a0, H1.bm0, c1, 0, 0, 0);
                c1 = __builtin_amdgcn_mfma_f32_16x16x32_bf16(a1, H1.bm1, c1, 0, 0, 0);
                const short4b uc0 = (kt == 0) ? H0.u0 : (kt == 1) ? H0.u1 : (kt == 2) ? H0.u2 : H0.u3;
                const short4b uc1 = (kt == 0) ? H1.u0 : (kt == 1) ? H1.u1 : (kt == 2) ? H1.u2 : H1.u3;
#pragma unroll
                for (int rg = 0; rg < 4; ++rg) {
                    p0 = fmaf(bf2f(uc0[rg]), c0[rg], p0);
                    p1 = fmaf(bf2f(uc1[rg]), c1[rg], p1);
                }
            }
            p0 += __shfl_xor(p0, 16); p0 += __shfl_xor(p0, 32);
            p1 += __shfl_xor(p1, 16); p1 += __shfl_xor(p1, 32);
            lg0[r] = p0; lg1[r] = p1;
        }
        finish(lg0, 0);
        finish(lg1, 1);
        const size_t o = (size_t)gg * 160;
        const size_t lim = (size_t)E * RR;
        float* og = out + o;
        if (o + lane < lim)                    og[lane]       = st[wid][lane];
        if (o + 64 + lane < lim)               og[64 + lane]  = st[wid][64 + lane];
        if (lane < 32 && o + 128 + lane < lim) og[128 + lane] = st[wid][128 + lane];
    };

    // ---- 2-deep ping-pong pipeline: idx 2 groups ahead, rows 1 ahead ----
    Half A0, A1, B0, B1;
    int iuA0, imA0, iuA1, imA1, iuB0, imB0, iuB1, imB1;
    int gA = g, gB = g + NW;
    ldidx(gA, 0, iuA0, imA0); ldidx(gA, 1, iuA1, imA1);
    ldrows(iuA0, imA0, A0);   ldrows(iuA1, imA1, A1);
    ldidx(gB, 0, iuB0, imB0); ldidx(gB, 1, iuB1, imB1);
    const int nsteps = (ng - 1 - g) / NW + 1;

    for (int i = 0; i < nsteps; i += 2) {
        ldrows(iuB0, imB0, B0); ldrows(iuB1, imB1, B1);
        ldidx(gA + 2 * NW, 0, iuA0, imA0); ldidx(gA + 2 * NW, 1, iuA1, imA1);
        compute2(A0, A1, gA);

        ldrows(iuA0, imA0, A0); ldrows(iuA1, imA1, A1);
        ldidx(gB + 2 * NW, 0, iuB0, imB0); ldidx(gB + 2 * NW, 1, iuB1, imB1);
        if (i + 1 < nsteps) compute2(B0, B1, gB);

        gA += 2 * NW;
        gB += 2 * NW;
    }
}

// ---------------- fallback (verified round-3 kernel) if ws too small ----------------
struct Rows {
    f32x4 m0, m1, m2, m3;
    f32x4 u0, u1, u2, u3;
};
__launch_bounds__(256, 2)
__global__ void bilinear_fp32_kernel(
    const float* __restrict__ z_user, const float* __restrict__ z_movie,
    const int* __restrict__ eidx, const float* __restrict__ Qm,
    float* __restrict__ out, int E)
{
    const int lane = threadIdx.x & 63;
    const int wid  = threadIdx.x >> 6;
    const int q    = lane >> 4;
    const int lm   = lane & 15;
    __shared__ float st_lds[4][80];

    short8 Aq[RR][4][2];
#pragma unroll
    for (int r = 0; r < RR; ++r)
#pragma unroll
        for (int kt = 0; kt < 4; ++kt)
#pragma unroll
            for (int s = 0; s < 2; ++s) {
                const float* src = Qm + (((size_t)r * DD + kt * 16 + lm) * DD + s * 32 + q * 8);
                Aq[r][kt][s] = pack_bf16(*(const f32x4*)src, *(const f32x4*)(src + 4));
            }
    const int ngroups = (E + 15) >> 4;
    const int nw = gridDim.x << 2;
    const int g0 = (blockIdx.x << 2) + wid;
    if (g0 >= ngroups) return;
    const int nsteps = (ngroups - 1 - g0) / nw + 1;

    auto ld_idx = [&](int g, int& iu, int& im) {
        int gg = g < ngroups ? g : (ngroups - 1);
        int e = (gg << 4) + lm;
        if (e >= E) e = E - 1;
        iu = eidx[e]; im = eidx[E + e];
    };
    auto ld_rows = [&](int iu, int im, Rows& R_) {
        const float* mr = z_movie + ((size_t)im << 6);
        const float* ur = z_user  + ((size_t)iu << 6);
        R_.m0 = *(const f32x4*)(mr + q * 8);      R_.m1 = *(const f32x4*)(mr + q * 8 + 4);
        R_.m2 = *(const f32x4*)(mr + 32 + q * 8); R_.m3 = *(const f32x4*)(mr + 32 + q * 8 + 4);
        R_.u0 = *(const f32x4*)(ur + q * 4);      R_.u1 = *(const f32x4*)(ur + 16 + q * 4);
        R_.u2 = *(const f32x4*)(ur + 32 + q * 4); R_.u3 = *(const f32x4*)(ur + 48 + q * 4);
    };
    auto compute = [&](const Rows& R_, int g, bool store) {
        const short8 Bm0 = pack_bf16(R_.m0, R_.m1);
        const short8 Bm1 = pack_bf16(R_.m2, R_.m3);
        float lg[RR];
#pragma unroll
        for (int r = 0; r < RR; ++r) {
            float p = 0.f;
#pragma unroll
            for (int kt = 0; kt < 4; ++kt) {
                f32x4 c = {0.f, 0.f, 0.f, 0.f};
                c = __builtin_amdgcn_mfma_f32_16x16x32_bf16(Aq[r][kt][0], Bm0, c, 0, 0, 0);
                c = __builtin_amdgcn_mfma_f32_16x16x32_bf16(Aq[r][kt][1], Bm1, c, 0, 0, 0);
                const f32x4 uf = (kt == 0) ? R_.u0 : (kt == 1) ? R_.u1 : (kt == 2) ? R_.u2 : R_.u3;
#pragma unroll
                for (int rg = 0; rg < 4; ++rg) p = fmaf(uf[rg], c[rg], p);
            }
            p += __shfl_xor(p, 16); p += __shfl_xor(p, 32);
            lg[r] = p;
        }
        float mx = lg[0];
#pragma unroll
        for (int r = 1; r < RR; ++r) mx = fmaxf(mx, lg[r]);
        float sum = 0.f;
#pragma unroll
        for (int r = 0; r < RR; ++r) sum += __expf(lg[r] - mx);
        const float sub = mx + __logf(sum);
        const float v0 = (q == 0) ? lg[0] : (q == 1) ? lg[1] : (q == 2) ? lg[2] : lg[3];
        st_lds[wid][lm * 5 + q] = v0 - sub;
        if (q == 0) st_lds[wid][lm * 5 + 4] = lg[4] - sub;
        if (store) {
            const size_t o = (size_t)g * (16 * RR);
            const size_t lim = (size_t)E * RR;
            if (o + lane < lim)                   out[o + lane]      = st_lds[wid][lane];
            if (lane < 16 && o + 64 + lane < lim) out[o + 64 + lane] = st_lds[wid][64 + lane];
        }
    };
    int iuA, imA, iuB, imB;
    Rows RA, RB;
    int gA = g0, gB = g0 + nw;
    ld_idx(gA, iuA, imA);
    ld_rows(iuA, imA, RA);
    ld_idx(gB, iuB, imB);
    for (int i = 0; i < nsteps; i += 2) {
        ld_rows(iuB, imB, RB);
        ld_idx(gA + 2 * nw, iuA, imA);
        compute(RA, gA, true);
        ld_rows(iuA, imA, RA);
        ld_idx(gB + 2 * nw, iuB, imB);
        compute(RB, gB, (i + 1) < nsteps);
        gA += 2 * nw; gB += 2 * nw;
    }
}

extern "C" void kernel_launch(void* const* d_in, const int* in_sizes, int n_in,
                              void* d_out, int out_size, void* d_ws, size_t ws_size,
                              hipStream_t stream) {
    const float* z_user  = (const float*)d_in[0];
    const float* z_movie = (const float*)d_in[1];
    const int*   eidx    = (const int*)d_in[2];
    const float* Qm      = (const float*)d_in[3];
    float* out = (float*)d_out;

    const int E = in_sizes[2] / 2;
    const size_t need = ((size_t)in_sizes[0] + (size_t)in_sizes[1]) * sizeof(unsigned short);

    if (ws_size >= need) {
        unsigned short* zub = (unsigned short*)d_ws;
        unsigned short* zmb = zub + in_sizes[0];
        cvt_bf16_kernel<<<2048, 256, 0, stream>>>(z_user, in_sizes[0] / 8,
                                                  z_movie, in_sizes[1] / 8, zub, zmb);
        const int ng = (E + 31) >> 5;
        int nb = (ng + NWAVES - 1) / NWAVES;
        if (nb > 768) nb = 768;   // 3 blocks/CU (LDS 43.5KB) = 12 waves/CU, exactly resident
        bilinear_bf16_kernel<<<nb, BLOCK, 0, stream>>>(zub, zmb, eidx, Qm, out, E);
    } else {
        const int ngroups = (E + 15) >> 4;
        int nblocks = (ngroups + 3) / 4;
        if (nblocks > 512) nblocks = 512;
        bilinear_fp32_kernel<<<nblocks, 256, 0, stream>>>(z_user, z_movie, eidx, Qm, out, E);
    }
}